// Round 1
// 730.277 us; speedup vs baseline: 1.0836x; 1.0836x over previous
//
#include <hip/hip_runtime.h>

typedef unsigned short u16;
typedef unsigned int u32;
typedef __attribute__((ext_vector_type(8))) short short8;
typedef __attribute__((ext_vector_type(8))) u16 ushort8;
typedef __attribute__((ext_vector_type(4))) u16 ushort4_t;
typedef __attribute__((ext_vector_type(4))) float fx4;

#define DIMK 2048
#define NBLK 2000

typedef const __attribute__((address_space(1))) void* gp_t;
typedef __attribute__((address_space(3))) void* lp_t;

__device__ __forceinline__ u16 f2bf(float f) {
  u32 u = __float_as_uint(f);
  u32 r = (u + 0x7fffu + ((u >> 16) & 1u)) >> 16;
  return (u16)r;
}

__device__ __forceinline__ u32 fkey(float f) {
  u32 u = __float_as_uint(f);
  return (u & 0x80000000u) ? ~u : (u | 0x80000000u);
}
__device__ __forceinline__ float dekey(u32 k) {
  u32 u = (k & 0x80000000u) ? (k ^ 0x80000000u) : ~k;
  return __uint_as_float(u);
}

// ---------------------------------------------------------------------------
// Legacy 128x128 tile (kept for gram_kernel): C = A[row0..+128,:]*B[col0..+128,:]^T
// A,B row-major bf16 (u16), ld=2048. 256 threads = 4 waves (2x2 of 64x64).
// LDS: 8 blocks of 16 rows x 32 k (512 u16). XOR-swizzled granule layout
// g(row,kchunk) = row*4 + (kchunk ^ ((row>>1)&3)); zero ds_read_b128 conflicts
// (SQ_LDS_BANK_CONFLICT measured 0).
// ---------------------------------------------------------------------------
__device__ __forceinline__ void gemm_tile(const u16* __restrict__ Abase,
                                          const u16* __restrict__ Bbase,
                                          int row0, int col0,
                                          u16* lsA, u16* lsB,
                                          fx4 acc[4][4])
{
  const int tid  = threadIdx.x;
  const int wv   = tid >> 6;
  const int lane = tid & 63;
  const int wr   = wv & 1, wc = wv >> 1;
  const int quad = lane >> 4, lc = lane & 15;

  const int srow = wv * 32 + (lane >> 2);
  const int skel = (((lane & 3) ^ ((lane >> 3) & 3)) * 8);
  const u16* gA0 = Abase + (size_t)(row0 + srow) * DIMK + skel;
  const u16* gA1 = gA0 + (size_t)16 * DIMK;
  const u16* gB0 = Bbase + (size_t)(col0 + srow) * DIMK + skel;
  const u16* gB1 = gB0 + (size_t)16 * DIMK;
  u16* lA0 = lsA + wv * 1024;
  u16* lA1 = lsA + wv * 1024 + 512;
  u16* lB0 = lsB + wv * 1024;
  u16* lB1 = lsB + wv * 1024 + 512;

  const int fIntra = lc * 32 + ((quad ^ ((lc >> 1) & 3)) * 8);

#pragma unroll
  for (int mi = 0; mi < 4; mi++)
#pragma unroll
    for (int ni = 0; ni < 4; ni++)
      acc[mi][ni] = fx4{0.f, 0.f, 0.f, 0.f};

  for (int k0 = 0; k0 < DIMK; k0 += 32) {
    __syncthreads();
    __builtin_amdgcn_global_load_lds((gp_t)gA0, (lp_t)lA0, 16, 0, 0);
    __builtin_amdgcn_global_load_lds((gp_t)gA1, (lp_t)lA1, 16, 0, 0);
    __builtin_amdgcn_global_load_lds((gp_t)gB0, (lp_t)lB0, 16, 0, 0);
    __builtin_amdgcn_global_load_lds((gp_t)gB1, (lp_t)lB1, 16, 0, 0);
    gA0 += 32; gA1 += 32; gB0 += 32; gB1 += 32;
    __syncthreads();
    short8 af[4], bfr[4];
#pragma unroll
    for (int mi = 0; mi < 4; mi++)
      af[mi] = *(const short8*)(lsA + (wr * 4 + mi) * 512 + fIntra);
#pragma unroll
    for (int ni = 0; ni < 4; ni++)
      bfr[ni] = *(const short8*)(lsB + (wc * 4 + ni) * 512 + fIntra);
#pragma unroll
    for (int mi = 0; mi < 4; mi++)
#pragma unroll
      for (int ni = 0; ni < 4; ni++)
        acc[mi][ni] = __builtin_amdgcn_mfma_f32_16x16x32_bf16(af[mi], bfr[ni], acc[mi][ni], 0, 0, 0);
  }
}

// one wave per row; block = 4 waves = 4 rows. No LDS, no __syncthreads.
__global__ __launch_bounds__(256) void norm_rows_x(const float* __restrict__ x,
                                                   u16* __restrict__ Xn)
{
  const int wv = threadIdx.x >> 6, lane = threadIdx.x & 63;
  const int row = blockIdx.x * 4 + wv;
  const float4* xr = (const float4*)(x + (size_t)row * DIMK);
  float4 v[8];
  float ss = 0.f;
#pragma unroll
  for (int j = 0; j < 8; j++) {
    v[j] = xr[j * 64 + lane];
    ss += v[j].x*v[j].x + v[j].y*v[j].y + v[j].z*v[j].z + v[j].w*v[j].w;
  }
#pragma unroll
  for (int off = 1; off < 64; off <<= 1) ss += __shfl_xor(ss, off);
  float inv = 1.0f / fmaxf(sqrtf(ss), 1e-12f);
  ushort4_t* o = (ushort4_t*)(Xn + (size_t)row * DIMK);
#pragma unroll
  for (int j = 0; j < 8; j++) {
    ushort4_t t;
    t[0] = f2bf(v[j].x * inv); t[1] = f2bf(v[j].y * inv);
    t[2] = f2bf(v[j].z * inv); t[3] = f2bf(v[j].w * inv);
    o[j * 64 + lane] = t;
  }
}

__global__ __launch_bounds__(256) void norm_rows_w(const float* __restrict__ w,
                                                   u16* __restrict__ Wn,
                                                   u16* __restrict__ Wb)
{
  const int wv = threadIdx.x >> 6, lane = threadIdx.x & 63;
  const int row = blockIdx.x * 4 + wv;
  ushort4_t* on_ = (ushort4_t*)(Wn + (size_t)row * DIMK);
  ushort4_t* ob_ = (ushort4_t*)(Wb + (size_t)row * DIMK);
  if (row < NBLK) {
    const float4* wr_ = (const float4*)(w + (size_t)row * DIMK);
    float4 v[8];
    float ss = 0.f;
#pragma unroll
    for (int j = 0; j < 8; j++) {
      v[j] = wr_[j * 64 + lane];
      ss += v[j].x*v[j].x + v[j].y*v[j].y + v[j].z*v[j].z + v[j].w*v[j].w;
    }
#pragma unroll
    for (int off = 1; off < 64; off <<= 1) ss += __shfl_xor(ss, off);
    float inv = 1.0f / fmaxf(sqrtf(ss), 1e-12f);
#pragma unroll
    for (int j = 0; j < 8; j++) {
      ushort4_t tn, tb;
      tn[0] = f2bf(v[j].x * inv); tn[1] = f2bf(v[j].y * inv);
      tn[2] = f2bf(v[j].z * inv); tn[3] = f2bf(v[j].w * inv);
      tb[0] = f2bf(v[j].x); tb[1] = f2bf(v[j].y);
      tb[2] = f2bf(v[j].z); tb[3] = f2bf(v[j].w);
      on_[j * 64 + lane] = tn;
      ob_[j * 64 + lane] = tb;
    }
  } else {
    ushort4_t z = ushort4_t{0, 0, 0, 0};
#pragma unroll
    for (int j = 0; j < 8; j++) { on_[j * 64 + lane] = z; ob_[j * 64 + lane] = z; }
  }
}

__global__ __launch_bounds__(256) void gram_kernel(const u16* __restrict__ Wb,
                                                   float* __restrict__ divsum)
{
  __shared__ __align__(16) u16 lsA[4096];
  __shared__ __align__(16) u16 lsB[4096];
  fx4 acc[4][4];
  const int i0 = blockIdx.y * 128, j0 = blockIdx.x * 128;
  gemm_tile(Wb, Wb, i0, j0, lsA, lsB, acc);
  const int tid = threadIdx.x, wv = tid >> 6, lane = tid & 63;
  const int wr = wv & 1, wc = wv >> 1, quad = lane >> 4, lc = lane & 15;
  float local = 0.f;
#pragma unroll
  for (int mi = 0; mi < 4; mi++) {
#pragma unroll
    for (int ni = 0; ni < 4; ni++) {
#pragma unroll
      for (int r = 0; r < 4; r++) {
        int i = i0 + wr * 64 + mi * 16 + quad * 4 + r;
        int j = j0 + wc * 64 + ni * 16 + lc;
        float g = acc[mi][ni][r];
        float d = (i == j && i < NBLK) ? 1.0f : 0.0f;
        float e = g - d;
        local += e * e;
      }
    }
  }
#pragma unroll
  for (int off = 1; off < 64; off <<= 1) local += __shfl_xor(local, off);
  if (lane == 0) atomicAdd(divsum, local);
}

// ---------------------------------------------------------------------------
// att: 256x256 tile, 8 waves (2M x 4N, 128x64 per wave), BK=32,
// 4-slot LDS ring (4 x 32KB = 128KB), counted vmcnt pipeline (T3+T4),
// setprio around MFMA cluster (T5), bijective XCD chunking (T1).
//
// Pipeline invariant (provable, no schedule dependence):
//   iter t:  vmcnt(8) -> this wave's tile-t loads landed (tiles t+1,t+2 may
//            be in flight);  s_barrier -> ALL waves' tile-t loads landed and
//            all waves finished iter t-1's ds_reads;  then issue tile t+3
//            into slot (t+3)&3 == (t-1)&3 (its readers all passed barrier);
//            ds_read slot t&3; 32 MFMA.
// One raw barrier per K-step; vmcnt never drains to 0 until the 3-iter tail.
// Same zero-conflict granule swizzle as gemm_tile, scaled to 16 blocks/operand.
// ---------------------------------------------------------------------------
__global__ __launch_bounds__(512, 2) void att_kernel(const u16* __restrict__ Xn,
                                                     const u16* __restrict__ Wn,
                                                     const int* __restrict__ mask,
                                                     u32* __restrict__ top1k,
                                                     float* __restrict__ s)
{
  __shared__ __align__(16) u16 ring[4][2][8192];  // [slot][A|B][16 blocks * 512]

  // bijective XCD chunk swizzle: nwg=1024, 8 XCDs -> each XCD gets 128
  // consecutive work ids = 16 contiguous row panels x all 8 col tiles.
  const int orig = blockIdx.x;
  const int wg   = ((orig & 7) << 7) | (orig >> 3);
  const int xb   = wg & 7;        // col tile (0..7)
  const int yb   = wg >> 3;       // row panel (0..127)
  const int row0 = yb << 8, col0 = xb << 8;

  const int tid  = threadIdx.x;
  const int wv   = tid >> 6, lane = tid & 63;
  const int wr   = wv >> 2, wc = wv & 3;           // 2M x 4N wave grid
  const int quad = lane >> 4, lc = lane & 15;

  // staging: wave wv covers rows wv*32..+32 of each operand tile (2 blocks)
  const int srow = wv * 32 + (lane >> 2);
  const int skel = (((lane & 3) ^ ((lane >> 3) & 3)) << 3);
  const u16* gA0 = Xn + (size_t)(row0 + srow) * DIMK + skel;
  const u16* gA1 = gA0 + (size_t)16 * DIMK;
  const u16* gB0 = Wn + (size_t)(col0 + srow) * DIMK + skel;
  const u16* gB1 = gB0 + (size_t)16 * DIMK;

  const int fIntra = lc * 32 + ((quad ^ ((lc >> 1) & 3)) << 3);

  fx4 acc[8][4];
#pragma unroll
  for (int mi = 0; mi < 8; mi++)
#pragma unroll
    for (int ni = 0; ni < 4; ni++)
      acc[mi][ni] = fx4{0.f, 0.f, 0.f, 0.f};

#define STAGE(slot, kt)                                                          \
  do {                                                                           \
    const int ko_ = (kt) << 5;                                                   \
    u16* lA_ = &ring[(slot)][0][wv << 10];                                       \
    u16* lB_ = &ring[(slot)][1][wv << 10];                                       \
    __builtin_amdgcn_global_load_lds((gp_t)(gA0 + ko_), (lp_t)lA_,         16, 0, 0); \
    __builtin_amdgcn_global_load_lds((gp_t)(gA1 + ko_), (lp_t)(lA_ + 512), 16, 0, 0); \
    __builtin_amdgcn_global_load_lds((gp_t)(gB0 + ko_), (lp_t)lB_,         16, 0, 0); \
    __builtin_amdgcn_global_load_lds((gp_t)(gB1 + ko_), (lp_t)(lB_ + 512), 16, 0, 0); \
  } while (0)

  STAGE(0, 0);
  STAGE(1, 1);
  STAGE(2, 2);

  const int NT = DIMK / 32;  // 64
  for (int t = 0; t < NT; ++t) {
    // tile t landed for this wave (4 loads/tile; allow 2 newest tiles in flight)
    if (t <= NT - 3)      asm volatile("s_waitcnt vmcnt(8)" ::: "memory");
    else if (t == NT - 2) asm volatile("s_waitcnt vmcnt(4)" ::: "memory");
    else                  asm volatile("s_waitcnt vmcnt(0)" ::: "memory");
    __builtin_amdgcn_s_barrier();
    __builtin_amdgcn_sched_barrier(0);

    if (t + 3 < NT) STAGE((t + 3) & 3, t + 3);

    const u16* lAt = &ring[t & 3][0][0];
    const u16* lBt = &ring[t & 3][1][0];
    short8 af[8], bfr[4];
#pragma unroll
    for (int mi = 0; mi < 8; mi++)
      af[mi] = *(const short8*)(lAt + (wr * 8 + mi) * 512 + fIntra);
#pragma unroll
    for (int ni = 0; ni < 4; ni++)
      bfr[ni] = *(const short8*)(lBt + (wc * 4 + ni) * 512 + fIntra);

    __builtin_amdgcn_s_setprio(1);
#pragma unroll
    for (int mi = 0; mi < 8; mi++)
#pragma unroll
      for (int ni = 0; ni < 4; ni++)
        acc[mi][ni] = __builtin_amdgcn_mfma_f32_16x16x32_bf16(af[mi], bfr[ni], acc[mi][ni], 0, 0, 0);
    __builtin_amdgcn_s_setprio(0);
  }
#undef STAGE

  // ---- epilogue: per-row max over this tile's 256 cols ----
#pragma unroll
  for (int mi = 0; mi < 8; mi++) {
#pragma unroll
    for (int r = 0; r < 4; r++) {
      float v = -3.0e38f;
#pragma unroll
      for (int ni = 0; ni < 4; ni++) {
        int col = col0 + wc * 64 + ni * 16 + lc;
        float av = acc[mi][ni][r];
        v = (col < NBLK && av > v) ? av : v;
      }
      v = fmaxf(v, __shfl_xor(v, 1));
      v = fmaxf(v, __shfl_xor(v, 2));
      v = fmaxf(v, __shfl_xor(v, 4));
      v = fmaxf(v, __shfl_xor(v, 8));
      if (lc == 0) {
        int row = row0 + wr * 128 + mi * 16 + quad * 4 + r;
        atomicMax(&top1k[row], fkey(v));
      }
    }
  }

  // ---- masked column sums for first half-batch -> s[b][col] ----
  if (yb < 64) {
    const int b = yb >> 2;
    float sv[4] = {0.f, 0.f, 0.f, 0.f};
#pragma unroll
    for (int mi = 0; mi < 8; mi++) {
#pragma unroll
      for (int r = 0; r < 4; r++) {
        float mval = (float)mask[row0 + wr * 128 + mi * 16 + quad * 4 + r];
#pragma unroll
        for (int ni = 0; ni < 4; ni++)
          sv[ni] += mval * acc[mi][ni][r];
      }
    }
#pragma unroll
    for (int ni = 0; ni < 4; ni++) {
      float v = sv[ni];
      v += __shfl_xor(v, 16);
      v += __shfl_xor(v, 32);
      int col = col0 + wc * 64 + ni * 16 + lc;
      if (quad == 0 && col < NBLK)
        atomicAdd(&s[b * 2048 + col], v);
    }
  }
}

__global__ __launch_bounds__(256) void softmax_kernel(const float* __restrict__ s,
                                                      float* __restrict__ tmp)
{
  const int b = blockIdx.x, tid = threadIdx.x;
  const float* sb = s + b * 2048;
  __shared__ float red[4];
  float mx = -3.0e38f;
  for (int n = tid; n < NBLK; n += 256) mx = fmaxf(mx, sb[n]);
#pragma unroll
  for (int off = 1; off < 64; off <<= 1) mx = fmaxf(mx, __shfl_xor(mx, off));
  if ((tid & 63) == 0) red[tid >> 6] = mx;
  __syncthreads();
  mx = fmaxf(fmaxf(red[0], red[1]), fmaxf(red[2], red[3]));
  __syncthreads();
  float se = 0.f;
  for (int n = tid; n < NBLK; n += 256) se += expf(sb[n] - mx);
#pragma unroll
  for (int off = 1; off < 64; off <<= 1) se += __shfl_xor(se, off);
  if ((tid & 63) == 0) red[tid >> 6] = se;
  __syncthreads();
  se = red[0] + red[1] + red[2] + red[3];
  float scale = 1.0f / (se * 16.0f);
  for (int n = tid; n < NBLK; n += 256) atomicAdd(&tmp[n], expf(sb[n] - mx) * scale);
}

__global__ __launch_bounds__(1024) void finalize_kernel(const u32* __restrict__ top1k,
                                                        const int* __restrict__ mask,
                                                        const float* __restrict__ tmp,
                                                        const float* __restrict__ divsum,
                                                        float* __restrict__ out)
{
  const int tid = threadIdx.x;
  __shared__ float sMin[32];
  __shared__ float sSq[16];
  const int b = tid >> 5, li = tid & 31;
  float mn = 3.0e38f;
  for (int t = li; t < 1024; t += 32) {
    int idx = b * 1024 + t;
    if (mask[idx] > 0) mn = fminf(mn, dekey(top1k[idx]));
  }
#pragma unroll
  for (int off = 1; off < 32; off <<= 1) mn = fminf(mn, __shfl_xor(mn, off));
  if (li == 0) sMin[b] = mn;
  float ssq = 0.f;
  for (int n = tid; n < NBLK; n += 1024) { float v = tmp[n]; ssq += v * v; }
#pragma unroll
  for (int off = 1; off < 64; off <<= 1) ssq += __shfl_xor(ssq, off);
  if ((tid & 63) == 0) sSq[tid >> 6] = ssq;
  __syncthreads();
  if (tid == 0) {
    float m0 = 0.f, m1 = 0.f;
    for (int i = 0; i < 16; i++) { m0 += sMin[i]; m1 += sMin[16 + i]; }
    m0 *= (1.0f / 16.0f); m1 *= (1.0f / 16.0f);
    float sq = 0.f;
    for (int i = 0; i < 16; i++) sq += sSq[i];
    out[0] = 0.2f * sqrtf(divsum[0]);
    out[1] = 2.0f - m0 + m1;
    out[2] = 0.5f * sqrtf(sq);
  }
}

extern "C" void kernel_launch(void* const* d_in, const int* in_sizes, int n_in,
                              void* d_out, int out_size, void* d_ws, size_t ws_size,
                              hipStream_t stream) {
  const float* x    = (const float*)d_in[0];   // [32,1024,2048] f32
  const int*   mask = (const int*)d_in[1];     // [32,1024] i32
  const float* w    = (const float*)d_in[2];   // [2000,2048] f32
  float* out = (float*)d_out;

  char* ws = (char*)d_ws;
  // layout: [top1k 128KB][s 128KB][tmp 8KB][divsum 256B][Xn 128MB][Wn 8MB][Wb 8MB]
  u32*   top1k  = (u32*)(ws);
  float* s      = (float*)(ws + 131072);
  float* tmp    = (float*)(ws + 262144);
  float* divsum = (float*)(ws + 270336);
  u16*   Xn     = (u16*)(ws + 270592);
  u16*   Wn     = (u16*)(ws + 270592 + 134217728ull);
  u16*   Wb     = (u16*)(ws + 270592 + 134217728ull + 8388608ull);

  hipMemsetAsync(ws, 0, 270592, stream);  // zero accumulators + top1 keys

  norm_rows_w<<<dim3(512), dim3(256), 0, stream>>>(w, Wn, Wb);
  norm_rows_x<<<dim3(8192), dim3(256), 0, stream>>>(x, Xn);
  gram_kernel<<<dim3(16, 16), dim3(256), 0, stream>>>(Wb, divsum);
  att_kernel<<<dim3(1024), dim3(512), 0, stream>>>(Xn, Wn, mask, top1k, s);
  softmax_kernel<<<dim3(16), dim3(256), 0, stream>>>(s, tmp);
  finalize_kernel<<<dim3(1), dim3(1024), 0, stream>>>(top1k, mask, tmp, divsum, out);
}

// Round 3
// 724.741 us; speedup vs baseline: 1.0919x; 1.0076x over previous
//
#include <hip/hip_runtime.h>

typedef unsigned short u16;
typedef unsigned int u32;
typedef __attribute__((ext_vector_type(8))) short short8;
typedef __attribute__((ext_vector_type(8))) u16 ushort8;
typedef __attribute__((ext_vector_type(4))) u16 ushort4_t;
typedef __attribute__((ext_vector_type(4))) float fx4;

#define DIMK 2048
#define NBLK 2000

typedef const __attribute__((address_space(1))) void* gp_t;
typedef __attribute__((address_space(3))) void* lp_t;

__device__ __forceinline__ u16 f2bf(float f) {
  u32 u = __float_as_uint(f);
  u32 r = (u + 0x7fffu + ((u >> 16) & 1u)) >> 16;
  return (u16)r;
}

__device__ __forceinline__ u32 fkey(float f) {
  u32 u = __float_as_uint(f);
  return (u & 0x80000000u) ? ~u : (u | 0x80000000u);
}
__device__ __forceinline__ float dekey(u32 k) {
  u32 u = (k & 0x80000000u) ? (k ^ 0x80000000u) : ~k;
  return __uint_as_float(u);
}

// ---------------------------------------------------------------------------
// Legacy 128x128 tile (kept for gram_kernel). Zero-conflict XOR granule
// swizzle, verified SQ_LDS_BANK_CONFLICT == 0.
// ---------------------------------------------------------------------------
__device__ __forceinline__ void gemm_tile(const u16* __restrict__ Abase,
                                          const u16* __restrict__ Bbase,
                                          int row0, int col0,
                                          u16* lsA, u16* lsB,
                                          fx4 acc[4][4])
{
  const int tid  = threadIdx.x;
  const int wv   = tid >> 6;
  const int lane = tid & 63;
  const int wr   = wv & 1, wc = wv >> 1;
  const int quad = lane >> 4, lc = lane & 15;

  const int srow = wv * 32 + (lane >> 2);
  const int skel = (((lane & 3) ^ ((lane >> 3) & 3)) * 8);
  const u16* gA0 = Abase + (size_t)(row0 + srow) * DIMK + skel;
  const u16* gA1 = gA0 + (size_t)16 * DIMK;
  const u16* gB0 = Bbase + (size_t)(col0 + srow) * DIMK + skel;
  const u16* gB1 = gB0 + (size_t)16 * DIMK;
  u16* lA0 = lsA + wv * 1024;
  u16* lA1 = lsA + wv * 1024 + 512;
  u16* lB0 = lsB + wv * 1024;
  u16* lB1 = lsB + wv * 1024 + 512;

  const int fIntra = lc * 32 + ((quad ^ ((lc >> 1) & 3)) * 8);

#pragma unroll
  for (int mi = 0; mi < 4; mi++)
#pragma unroll
    for (int ni = 0; ni < 4; ni++)
      acc[mi][ni] = fx4{0.f, 0.f, 0.f, 0.f};

  for (int k0 = 0; k0 < DIMK; k0 += 32) {
    __syncthreads();
    __builtin_amdgcn_global_load_lds((gp_t)gA0, (lp_t)lA0, 16, 0, 0);
    __builtin_amdgcn_global_load_lds((gp_t)gA1, (lp_t)lA1, 16, 0, 0);
    __builtin_amdgcn_global_load_lds((gp_t)gB0, (lp_t)lB0, 16, 0, 0);
    __builtin_amdgcn_global_load_lds((gp_t)gB1, (lp_t)lB1, 16, 0, 0);
    gA0 += 32; gA1 += 32; gB0 += 32; gB1 += 32;
    __syncthreads();
    short8 af[4], bfr[4];
#pragma unroll
    for (int mi = 0; mi < 4; mi++)
      af[mi] = *(const short8*)(lsA + (wr * 4 + mi) * 512 + fIntra);
#pragma unroll
    for (int ni = 0; ni < 4; ni++)
      bfr[ni] = *(const short8*)(lsB + (wc * 4 + ni) * 512 + fIntra);
#pragma unroll
    for (int mi = 0; mi < 4; mi++)
#pragma unroll
      for (int ni = 0; ni < 4; ni++)
        acc[mi][ni] = __builtin_amdgcn_mfma_f32_16x16x32_bf16(af[mi], bfr[ni], acc[mi][ni], 0, 0, 0);
  }
}

// one wave per row; block = 4 waves = 4 rows. No LDS, no __syncthreads.
__global__ __launch_bounds__(256) void norm_rows_x(const float* __restrict__ x,
                                                   u16* __restrict__ Xn)
{
  const int wv = threadIdx.x >> 6, lane = threadIdx.x & 63;
  const int row = blockIdx.x * 4 + wv;
  const float4* xr = (const float4*)(x + (size_t)row * DIMK);
  float4 v[8];
  float ss = 0.f;
#pragma unroll
  for (int j = 0; j < 8; j++) {
    v[j] = xr[j * 64 + lane];
    ss += v[j].x*v[j].x + v[j].y*v[j].y + v[j].z*v[j].z + v[j].w*v[j].w;
  }
#pragma unroll
  for (int off = 1; off < 64; off <<= 1) ss += __shfl_xor(ss, off);
  float inv = 1.0f / fmaxf(sqrtf(ss), 1e-12f);
  ushort4_t* o = (ushort4_t*)(Xn + (size_t)row * DIMK);
#pragma unroll
  for (int j = 0; j < 8; j++) {
    ushort4_t t;
    t[0] = f2bf(v[j].x * inv); t[1] = f2bf(v[j].y * inv);
    t[2] = f2bf(v[j].z * inv); t[3] = f2bf(v[j].w * inv);
    o[j * 64 + lane] = t;
  }
}

__global__ __launch_bounds__(256) void norm_rows_w(const float* __restrict__ w,
                                                   u16* __restrict__ Wn,
                                                   u16* __restrict__ Wb)
{
  const int wv = threadIdx.x >> 6, lane = threadIdx.x & 63;
  const int row = blockIdx.x * 4 + wv;
  ushort4_t* on_ = (ushort4_t*)(Wn + (size_t)row * DIMK);
  ushort4_t* ob_ = (ushort4_t*)(Wb + (size_t)row * DIMK);
  if (row < NBLK) {
    const float4* wr_ = (const float4*)(w + (size_t)row * DIMK);
    float4 v[8];
    float ss = 0.f;
#pragma unroll
    for (int j = 0; j < 8; j++) {
      v[j] = wr_[j * 64 + lane];
      ss += v[j].x*v[j].x + v[j].y*v[j].y + v[j].z*v[j].z + v[j].w*v[j].w;
    }
#pragma unroll
    for (int off = 1; off < 64; off <<= 1) ss += __shfl_xor(ss, off);
    float inv = 1.0f / fmaxf(sqrtf(ss), 1e-12f);
#pragma unroll
    for (int j = 0; j < 8; j++) {
      ushort4_t tn, tb;
      tn[0] = f2bf(v[j].x * inv); tn[1] = f2bf(v[j].y * inv);
      tn[2] = f2bf(v[j].z * inv); tn[3] = f2bf(v[j].w * inv);
      tb[0] = f2bf(v[j].x); tb[1] = f2bf(v[j].y);
      tb[2] = f2bf(v[j].z); tb[3] = f2bf(v[j].w);
      on_[j * 64 + lane] = tn;
      ob_[j * 64 + lane] = tb;
    }
  } else {
    ushort4_t z = ushort4_t{0, 0, 0, 0};
#pragma unroll
    for (int j = 0; j < 8; j++) { on_[j * 64 + lane] = z; ob_[j * 64 + lane] = z; }
  }
}

// Gram is symmetric: compute only tiles with by <= bx; off-diagonal tiles
// contribute twice. Blocks with by > bx exit immediately (uniform branch,
// before any barrier).
__global__ __launch_bounds__(256) void gram_kernel(const u16* __restrict__ Wb,
                                                   float* __restrict__ divsum)
{
  const int bx = blockIdx.x, by = blockIdx.y;
  if (by > bx) return;
  __shared__ __align__(16) u16 lsA[4096];
  __shared__ __align__(16) u16 lsB[4096];
  fx4 acc[4][4];
  const int i0 = by * 128, j0 = bx * 128;
  gemm_tile(Wb, Wb, i0, j0, lsA, lsB, acc);
  const int tid = threadIdx.x, wv = tid >> 6, lane = tid & 63;
  const int wr = wv & 1, wc = wv >> 1, quad = lane >> 4, lc = lane & 15;
  const float mult = (bx == by) ? 1.0f : 2.0f;
  float local = 0.f;
#pragma unroll
  for (int mi = 0; mi < 4; mi++) {
#pragma unroll
    for (int ni = 0; ni < 4; ni++) {
#pragma unroll
      for (int r = 0; r < 4; r++) {
        int i = i0 + wr * 64 + mi * 16 + quad * 4 + r;
        int j = j0 + wc * 64 + ni * 16 + lc;
        float g = acc[mi][ni][r];
        float d = (i == j && i < NBLK) ? 1.0f : 0.0f;
        float e = g - d;
        local += e * e;
      }
    }
  }
  local *= mult;
#pragma unroll
  for (int off = 1; off < 64; off <<= 1) local += __shfl_xor(local, off);
  if (lane == 0) atomicAdd(divsum, local);
}

// ---------------------------------------------------------------------------
// att: 256x256 tile, 8 waves (2M x 4N, 128x64 per wave), BK=32,
// 4-slot LDS ring (4 x 32KB), counted vmcnt (T4), XCD chunking (T1),
// and the m201-style 2-phase-per-K-step interleave (T3):
//   phase A: {read bfr[0..3]+af[0..3] (slot t); stage A-half(t+3); barrier;
//             lgkmcnt(0); setprio(1); 16 MFMA (mi 0..3); setprio(0); barrier}
//   phase B: {read af[4..7] (slot t); stage B-half(t+3); vmcnt(8); barrier;
//             lgkmcnt(0); setprio(1); 16 MFMA (mi 4..7); setprio(0); barrier}
// Waves pass the post-MFMA barrier right after ISSUING the MFMAs, so the next
// phase's ds_reads execute while the matrix pipe drains -> LDS and MFMA pipes
// overlap. vmcnt ledger: 12 outstanding (tiles t+1,t+2,t+3) -> vmcnt(8)
// confirms t+1; tail 8 -> vmcnt(4), 4 -> vmcnt(0). Slot (t+3)&3 == (t-1)&3
// rewrite is safe: its last readers completed (lgkmcnt(0)) before barriers
// all waves have since passed.
// ---------------------------------------------------------------------------
__global__ __launch_bounds__(512, 2) void att_kernel(const u16* __restrict__ Xn,
                                                     const u16* __restrict__ Wn,
                                                     const int* __restrict__ mask,
                                                     u32* __restrict__ top1k,
                                                     float* __restrict__ s)
{
  __shared__ __align__(16) u16 ring[4][2][8192];  // [slot][A|B][16 blocks * 512]

  // bijective XCD chunk swizzle: nwg=1024, 8 XCDs.
  const int orig = blockIdx.x;
  const int wg   = ((orig & 7) << 7) | (orig >> 3);
  const int xb   = wg & 7;        // col tile (0..7)
  const int yb   = wg >> 3;       // row panel (0..127)
  const int row0 = yb << 8, col0 = xb << 8;

  const int tid  = threadIdx.x;
  const int wv   = tid >> 6, lane = tid & 63;
  const int wr   = wv >> 2, wc = wv & 3;           // 2M x 4N wave grid
  const int quad = lane >> 4, lc = lane & 15;

  // staging: wave wv covers rows wv*32..+32 of each operand tile (2 blocks)
  const int srow = wv * 32 + (lane >> 2);
  const int skel = (((lane & 3) ^ ((lane >> 3) & 3)) << 3);
  const u16* gA0 = Xn + (size_t)(row0 + srow) * DIMK + skel;
  const u16* gA1 = gA0 + (size_t)16 * DIMK;
  const u16* gB0 = Wn + (size_t)(col0 + srow) * DIMK + skel;
  const u16* gB1 = gB0 + (size_t)16 * DIMK;

  const int fIntra = lc * 32 + ((quad ^ ((lc >> 1) & 3)) << 3);

  fx4 acc[8][4];
#pragma unroll
  for (int mi = 0; mi < 8; mi++)
#pragma unroll
    for (int ni = 0; ni < 4; ni++)
      acc[mi][ni] = fx4{0.f, 0.f, 0.f, 0.f};

#define STAGE_A(kt)                                                              \
  do {                                                                           \
    const int ko_ = (kt) << 5;                                                   \
    u16* lA_ = &ring[(kt) & 3][0][wv << 10];                                     \
    __builtin_amdgcn_global_load_lds((gp_t)(gA0 + ko_), (lp_t)lA_,         16, 0, 0); \
    __builtin_amdgcn_global_load_lds((gp_t)(gA1 + ko_), (lp_t)(lA_ + 512), 16, 0, 0); \
  } while (0)
#define STAGE_B(kt)                                                              \
  do {                                                                           \
    const int ko_ = (kt) << 5;                                                   \
    u16* lB_ = &ring[(kt) & 3][1][wv << 10];                                     \
    __builtin_amdgcn_global_load_lds((gp_t)(gB0 + ko_), (lp_t)lB_,         16, 0, 0); \
    __builtin_amdgcn_global_load_lds((gp_t)(gB1 + ko_), (lp_t)(lB_ + 512), 16, 0, 0); \
  } while (0)

#define K_ITER(T, VM, DO_STAGE)                                                  \
  do {                                                                           \
    const u16* lAt_ = &ring[(T) & 3][0][0];                                      \
    const u16* lBt_ = &ring[(T) & 3][1][0];                                      \
    short8 bfr[4], af0[4], af1[4];                                               \
    _Pragma("unroll") for (int q = 0; q < 4; q++)                                \
      bfr[q] = *(const short8*)(lBt_ + (wc * 4 + q) * 512 + fIntra);             \
    _Pragma("unroll") for (int q = 0; q < 4; q++)                                \
      af0[q] = *(const short8*)(lAt_ + (wr * 8 + q) * 512 + fIntra);             \
    if (DO_STAGE) STAGE_A((T) + 3);                                              \
    __builtin_amdgcn_s_barrier();                                                \
    asm volatile("s_waitcnt lgkmcnt(0)" ::: "memory");                           \
    __builtin_amdgcn_s_setprio(1);                                               \
    _Pragma("unroll") for (int mi = 0; mi < 4; mi++)                             \
      _Pragma("unroll") for (int ni = 0; ni < 4; ni++)                           \
        acc[mi][ni] = __builtin_amdgcn_mfma_f32_16x16x32_bf16(af0[mi], bfr[ni], acc[mi][ni], 0, 0, 0); \
    __builtin_amdgcn_s_setprio(0);                                               \
    __builtin_amdgcn_s_barrier();                                                \
    _Pragma("unroll") for (int q = 0; q < 4; q++)                                \
      af1[q] = *(const short8*)(lAt_ + (wr * 8 + 4 + q) * 512 + fIntra);         \
    if (DO_STAGE) STAGE_B((T) + 3);                                              \
    asm volatile("s_waitcnt " VM ::: "memory");                                  \
    __builtin_amdgcn_s_barrier();                                                \
    asm volatile("s_waitcnt lgkmcnt(0)" ::: "memory");                           \
    __builtin_amdgcn_s_setprio(1);                                               \
    _Pragma("unroll") for (int mi = 0; mi < 4; mi++)                             \
      _Pragma("unroll") for (int ni = 0; ni < 4; ni++)                           \
        acc[4 + mi][ni] = __builtin_amdgcn_mfma_f32_16x16x32_bf16(af1[mi], bfr[ni], acc[4 + mi][ni], 0, 0, 0); \
    __builtin_amdgcn_s_setprio(0);                                               \
    __builtin_amdgcn_s_barrier();                                                \
  } while (0)

  // prologue: stage tiles 0,1,2 (12 loads); confirm tile 0 (oldest 4)
  STAGE_A(0); STAGE_B(0);
  STAGE_A(1); STAGE_B(1);
  STAGE_A(2); STAGE_B(2);
  asm volatile("s_waitcnt vmcnt(8)" ::: "memory");
  __builtin_amdgcn_s_barrier();

  const int NT = DIMK / 32;  // 64
#pragma unroll 1
  for (int t = 0; t < NT - 4; ++t)
    K_ITER(t, "vmcnt(8)", 1);
  K_ITER(NT - 4, "vmcnt(8)", 1);   // t=60: stages tile 63
  K_ITER(NT - 3, "vmcnt(4)", 0);   // t=61: outstanding 62,63 -> confirm 62
  K_ITER(NT - 2, "vmcnt(0)", 0);   // t=62: confirm 63
  K_ITER(NT - 1, "vmcnt(0)", 0);   // t=63
#undef K_ITER
#undef STAGE_A
#undef STAGE_B

  // ---- epilogue: per-row max over this tile's 256 cols ----
#pragma unroll
  for (int mi = 0; mi < 8; mi++) {
#pragma unroll
    for (int r = 0; r < 4; r++) {
      float v = -3.0e38f;
#pragma unroll
      for (int ni = 0; ni < 4; ni++) {
        int col = col0 + wc * 64 + ni * 16 + lc;
        float av = acc[mi][ni][r];
        v = (col < NBLK && av > v) ? av : v;
      }
      v = fmaxf(v, __shfl_xor(v, 1));
      v = fmaxf(v, __shfl_xor(v, 2));
      v = fmaxf(v, __shfl_xor(v, 4));
      v = fmaxf(v, __shfl_xor(v, 8));
      if (lc == 0) {
        int row = row0 + wr * 128 + mi * 16 + quad * 4 + r;
        atomicMax(&top1k[row], fkey(v));
      }
    }
  }

  // ---- masked column sums for first half-batch -> s[b][col] ----
  if (yb < 64) {
    const int b = yb >> 2;
    float sv[4] = {0.f, 0.f, 0.f, 0.f};
#pragma unroll
    for (int mi = 0; mi < 8; mi++) {
#pragma unroll
      for (int r = 0; r < 4; r++) {
        float mval = (float)mask[row0 + wr * 128 + mi * 16 + quad * 4 + r];
#pragma unroll
        for (int ni = 0; ni < 4; ni++)
          sv[ni] += mval * acc[mi][ni][r];
      }
    }
#pragma unroll
    for (int ni = 0; ni < 4; ni++) {
      float v = sv[ni];
      v += __shfl_xor(v, 16);
      v += __shfl_xor(v, 32);
      int col = col0 + wc * 64 + ni * 16 + lc;
      if (quad == 0 && col < NBLK)
        atomicAdd(&s[b * 2048 + col], v);
    }
  }
}

__global__ __launch_bounds__(256) void softmax_kernel(const float* __restrict__ s,
                                                      float* __restrict__ tmp)
{
  const int b = blockIdx.x, tid = threadIdx.x;
  const float* sb = s + b * 2048;
  __shared__ float red[4];
  float mx = -3.0e38f;
  for (int n = tid; n < NBLK; n += 256) mx = fmaxf(mx, sb[n]);
#pragma unroll
  for (int off = 1; off < 64; off <<= 1) mx = fmaxf(mx, __shfl_xor(mx, off));
  if ((tid & 63) == 0) red[tid >> 6] = mx;
  __syncthreads();
  mx = fmaxf(fmaxf(red[0], red[1]), fmaxf(red[2], red[3]));
  __syncthreads();
  float se = 0.f;
  for (int n = tid; n < NBLK; n += 256) se += expf(sb[n] - mx);
#pragma unroll
  for (int off = 1; off < 64; off <<= 1) se += __shfl_xor(se, off);
  if ((tid & 63) == 0) red[tid >> 6] = se;
  __syncthreads();
  se = red[0] + red[1] + red[2] + red[3];
  float scale = 1.0f / (se * 16.0f);
  for (int n = tid; n < NBLK; n += 256) atomicAdd(&tmp[n], expf(sb[n] - mx) * scale);
}

__global__ __launch_bounds__(1024) void finalize_kernel(const u32* __restrict__ top1k,
                                                        const int* __restrict__ mask,
                                                        const float* __restrict__ tmp,
                                                        const float* __restrict__ divsum,
                                                        float* __restrict__ out)
{
  const int tid = threadIdx.x;
  __shared__ float sMin[32];
  __shared__ float sSq[16];
  const int b = tid >> 5, li = tid & 31;
  float mn = 3.0e38f;
  for (int t = li; t < 1024; t += 32) {
    int idx = b * 1024 + t;
    if (mask[idx] > 0) mn = fminf(mn, dekey(top1k[idx]));
  }
#pragma unroll
  for (int off = 1; off < 32; off <<= 1) mn = fminf(mn, __shfl_xor(mn, off));
  if (li == 0) sMin[b] = mn;
  float ssq = 0.f;
  for (int n = tid; n < NBLK; n += 1024) { float v = tmp[n]; ssq += v * v; }
#pragma unroll
  for (int off = 1; off < 64; off <<= 1) ssq += __shfl_xor(ssq, off);
  if ((tid & 63) == 0) sSq[tid >> 6] = ssq;
  __syncthreads();
  if (tid == 0) {
    float m0 = 0.f, m1 = 0.f;
    for (int i = 0; i < 16; i++) { m0 += sMin[i]; m1 += sMin[16 + i]; }
    m0 *= (1.0f / 16.0f); m1 *= (1.0f / 16.0f);
    float sq = 0.f;
    for (int i = 0; i < 16; i++) sq += sSq[i];
    out[0] = 0.2f * sqrtf(divsum[0]);
    out[1] = 2.0f - m0 + m1;
    out[2] = 0.5f * sqrtf(sq);
  }
}

extern "C" void kernel_launch(void* const* d_in, const int* in_sizes, int n_in,
                              void* d_out, int out_size, void* d_ws, size_t ws_size,
                              hipStream_t stream) {
  const float* x    = (const float*)d_in[0];   // [32,1024,2048] f32
  const int*   mask = (const int*)d_in[1];     // [32,1024] i32
  const float* w    = (const float*)d_in[2];   // [2000,2048] f32
  float* out = (float*)d_out;

  char* ws = (char*)d_ws;
  // layout: [top1k 128KB][s 128KB][tmp 8KB][divsum 256B][Xn 128MB][Wn 8MB][Wb 8MB]
  u32*   top1k  = (u32*)(ws);
  float* s      = (float*)(ws + 131072);
  float* tmp    = (float*)(ws + 262144);
  float* divsum = (float*)(ws + 270336);
  u16*   Xn     = (u16*)(ws + 270592);
  u16*   Wn     = (u16*)(ws + 270592 + 134217728ull);
  u16*   Wb     = (u16*)(ws + 270592 + 134217728ull + 8388608ull);

  hipMemsetAsync(ws, 0, 270592, stream);  // zero accumulators + top1 keys

  norm_rows_w<<<dim3(512), dim3(256), 0, stream>>>(w, Wn, Wb);
  norm_rows_x<<<dim3(8192), dim3(256), 0, stream>>>(x, Xn);
  gram_kernel<<<dim3(16, 16), dim3(256), 0, stream>>>(Wb, divsum);
  att_kernel<<<dim3(1024), dim3(512), 0, stream>>>(Xn, Wn, mask, top1k, s);
  softmax_kernel<<<dim3(16), dim3(256), 0, stream>>>(s, tmp);
  finalize_kernel<<<dim3(1), dim3(1024), 0, stream>>>(top1k, mask, tmp, divsum, out);
}